// Round 5
// baseline (260.122 us; speedup 1.0000x reference)
//
#include <hip/hip_runtime.h>
#include <hip/hip_fp16.h>

#define N_NODES 50000
#define N_EDGES 800000
#define DIM 128
#define NUM_GRAPHS 128
#define STRIDE 64                      // CSR slot stride (>= max in-degree)
#define PSLICE 6272                    // padded nodes/slice (392 x 128 B lines)

#define ATTR_SCALE 33554432.0f         // 2^25 fixed-point for attr sums
#define ATTR_MASK  ((1ull << 40) - 1)

typedef _Float16 f16x8 __attribute__((ext_vector_type(8)));
typedef float f32x4 __attribute__((ext_vector_type(4)));

// ===========================================================================
// H / A layout (R15): COLUMN-PLANE-BLOCKED fp16 (4 planes of [n][64 B]).
// R16 (NT epack): REGRESSED 256->300 us — epack is read 4x (once per cg)
//   from different XCDs; nt killed cross-cg L2 reuse. Plain loads.
// R17 (16-wide gather): NEUTRAL — gather ILP not the limiter. 8-wide kept.
// R18 (slice-grouped packed): NULL — atomics execute memory-side at the
//   coherent point; XCD affinity of the issuing wave is irrelevant. Layout
//   kept (harmless).
// R19: UN-SLICED k_build. The 8x XCD slicing replicated the edge scan
//   (100K waves, 25.6 MB redundant dst fetch, 7/8 lanes filtered) for an
//   affinity benefit R18 disproved. One pass: 12.5K waves, every lane
//   active, dst/attr/src read once. Atomic count unchanged. Edge rank
//   order changes -> gather sum order changes (fp32, within tolerance);
//   fixed-point attr sum is order-exact.
// ===========================================================================

__device__ __forceinline__ int pidx(int d) {
    return (d & 7) * PSLICE + (d >> 3);
}

// ===== fused one-pass CSR build + W-transpose ==============================

__global__ __launch_bounds__(256) void k_build(const int* __restrict__ src,
                                               const int* __restrict__ dst,
                                               const float* __restrict__ attr,
                                               const float* __restrict__ W0,
                                               const float* __restrict__ W1,
                                               unsigned long long* packed,
                                               unsigned int* __restrict__ epack,
                                               _Float16* __restrict__ Wt0,
                                               _Float16* __restrict__ Wt1,
                                               int E, int nbChunks) {
    int b = blockIdx.x;
    if (b >= nbChunks) {
        int idx = (b - nbChunks) * 256 + threadIdx.x;  // 32768 = 2*128*128
        int m = idx >> 14;
        int rem = idx & 16383;
        int n = rem >> 7;
        int k = rem & 127;
        const float* W = m ? W1 : W0;
        _Float16* Wt = m ? Wt1 : Wt0;
        Wt[(size_t)n * 128 + k] = (_Float16)W[(size_t)k * 128 + n];
        return;
    }
    int e = b * 256 + threadIdx.x;
    if (e >= E) return;
    int d = dst[e];
    float a = attr[e];
    unsigned long long add =
        (1ull << 40) | (unsigned long long)(unsigned int)(a * ATTR_SCALE + 0.5f);
    unsigned long long old = atomicAdd(&packed[pidx(d)], add);
    int rank = (int)(old >> 40);
    if (rank < STRIDE) {
        __half ha = __float2half_rn(a);
        unsigned short us = *reinterpret_cast<unsigned short*>(&ha);
        epack[d * STRIDE + rank] = ((unsigned int)us << 16) | (unsigned int)src[e];
    }
}

// ===== MFMA f16 GEMM, operand-swapped ======================================
// float path (layer 1): A = x, row-major fp32 (external input).
// f16 path (layer 2):   A = bufA16, PLANE-BLOCKED (written by k_gather<false>).
// H output: PLANE-BLOCKED. colq = quad + 4t -> plane (colq>>3), offset colq&7.

template <typename AT>
__global__ __launch_bounds__(256) void k_gemm_mfma(const AT* __restrict__ A,
                                                   const _Float16* __restrict__ Wt,
                                                   const unsigned long long* __restrict__ packed,
                                                   __half* __restrict__ H, int n) {
    int tid = threadIdx.x;
    int w = tid >> 6, lane = tid & 63;
    int n15 = lane & 15, quad = lane >> 4;
    int node = blockIdx.x * 64 + w * 16 + n15;
    int nodec = node < n ? node : n - 1;
    const AT* Arow = A + (size_t)nodec * DIM;   // used by float path only

    f32x4 acc[8];
#pragma unroll
    for (int t = 0; t < 8; t++) acc[t] = (f32x4){0.f, 0.f, 0.f, 0.f};

#pragma unroll
    for (int c = 0; c < 4; c++) {
        f16x8 bf;
        if constexpr (__is_same(AT, float)) {
            float4 a0 = ((const float4*)Arow)[c * 8 + quad * 2];
            float4 a1 = ((const float4*)Arow)[c * 8 + quad * 2 + 1];
            bf[0] = (_Float16)a0.x; bf[1] = (_Float16)a0.y;
            bf[2] = (_Float16)a0.z; bf[3] = (_Float16)a0.w;
            bf[4] = (_Float16)a1.x; bf[5] = (_Float16)a1.y;
            bf[6] = (_Float16)a1.z; bf[7] = (_Float16)a1.w;
        } else {
            // plane-blocked read: f16x8 = 2 uint2 at plane c, offset quad*2.
            const uint2* Ab = reinterpret_cast<const uint2*>(A);
            bf = *(const f16x8*)&Ab[((size_t)c * n + nodec) * 8 + quad * 2];
        }
#pragma unroll
        for (int t = 0; t < 8; t++) {
            f16x8 af = *(const f16x8*)(Wt + (size_t)(t * 16 + n15) * 128 + c * 32 + quad * 8);
            acc[t] = __builtin_amdgcn_mfma_f32_16x16x32_f16(af, bf, acc[t], 0, 0, 0);
        }
    }

    if (node < n) {
        unsigned long long pk = packed[pidx(nodec)];
        float dv = rsqrtf(1.0f + (float)(pk & ATTR_MASK) * (1.0f / ATTR_SCALE));
        uint2* Hb = (uint2*)H;
#pragma unroll
        for (int t = 0; t < 8; t++) {
            __half2 h01 = __floats2half2_rn(acc[t][0] * dv, acc[t][1] * dv);
            __half2 h23 = __floats2half2_rn(acc[t][2] * dv, acc[t][3] * dv);
            uint2 pkd;
            pkd.x = *reinterpret_cast<unsigned int*>(&h01);
            pkd.y = *reinterpret_cast<unsigned int*>(&h23);
            int colq = quad + 4 * t;
            Hb[((size_t)(colq >> 3) * n + node) * 8 + (colq & 7)] = pkd;
        }
    }
}

// ===== COLUMN-SLICED gather, plane-blocked H (8-wide, R1 state) ============
// 8 lanes/node, cg = blockIdx&3 -> plane index == cg. Each cg's plane is
// 3.2 MB of fully-used lines. epack: PLAIN loads (cross-cg L2 reuse, R16).

__device__ __forceinline__ float2 unpack_h2(unsigned int u) {
    __half2 h = *reinterpret_cast<__half2*>(&u);
    return __half22float2(h);
}

template <bool POOL>
__global__ __launch_bounds__(256) void k_gather(const __half* __restrict__ H,
                                                const unsigned long long* __restrict__ packed,
                                                const unsigned int* __restrict__ epack,
                                                const float* __restrict__ bias,
                                                const int* __restrict__ batch,
                                                __half* __restrict__ OUT,
                                                float* gsum, float* cnt, int n) {
    int cg = blockIdx.x & 3;           // column group == plane (XCD-affine)
    int nb = blockIdx.x >> 2;          // node-block (32 nodes)
    int slot = threadIdx.x >> 3;       // node slot [0,32)
    int ln = threadIdx.x & 7;          // lane in group [0,8)
    int i = nb * 32 + slot;
    bool valid = i < n;
    int ic = valid ? i : n - 1;
    int colq = cg * 8 + ln;            // logical uint2 column [0,32) (bias/pool)
    const uint2* Hp = (const uint2*)H + (size_t)cg * n * 8;   // this cg's plane

    unsigned long long pk = packed[pidx(ic)];
    int cntE = valid ? (int)(pk >> 40) : 0;
    if (cntE > STRIDE) cntE = STRIDE;
    float dv = rsqrtf(1.0f + (float)(pk & ATTR_MASK) * (1.0f / ATTR_SCALE));

    uint2 selfraw = Hp[(size_t)ic * 8 + ln];
    float2 s01 = unpack_h2(selfraw.x);
    float2 s23 = unpack_h2(selfraw.y);
    float4 acc = make_float4(s01.x, s01.y, s23.x, s23.y);

    int j0 = ic * STRIDE;
    int end = j0 + cntE;

    for (int j = j0; j < end; j += 8) {
        int s[8];
        float wt[8];
#pragma unroll
        for (int k = 0; k < 8; k++) {
            int jj = j + k;
            bool v2 = jj < end;
            int jc = v2 ? jj : (end - 1);
            unsigned int pe = epack[jc];
            s[k] = (int)(pe & 0xffffu);
            __half_raw hr;
            hr.x = (unsigned short)(pe >> 16);
            wt[k] = v2 ? __half2float(__half(hr)) : 0.f;
        }
        uint2 v[8];
#pragma unroll
        for (int k = 0; k < 8; k++) v[k] = Hp[(size_t)s[k] * 8 + ln];
#pragma unroll
        for (int k = 0; k < 8; k++) {
            float2 f01 = unpack_h2(v[k].x);
            float2 f23 = unpack_h2(v[k].y);
            acc.x += wt[k] * f01.x;
            acc.y += wt[k] * f01.y;
            acc.z += wt[k] * f23.x;
            acc.w += wt[k] * f23.y;
        }
    }

    float4 bb = ((const float4*)bias)[colq];
    acc.x = fmaxf(acc.x * dv + bb.x, 0.f);
    acc.y = fmaxf(acc.y * dv + bb.y, 0.f);
    acc.z = fmaxf(acc.z * dv + bb.z, 0.f);
    acc.w = fmaxf(acc.w * dv + bb.w, 0.f);

    if constexpr (POOL) {
        __shared__ float lpool[32 * 32];  // 32 nodes x 32 feats (this cg)
        __shared__ int sg[32];
        __shared__ int meta[4];           // gA, gB, cntA, cntB
        if (ln == 0) sg[slot] = valid ? batch[ic] : -1;
        __syncthreads();
        if (threadIdx.x == 0) {
            int nv = n - nb * 32; if (nv > 32) nv = 32;
            int gA = sg[0];
            int gB = sg[nv - 1];
            int cA = 0, cB = 0;
            for (int k2 = 0; k2 < nv; k2++) {
                if (sg[k2] == gA) cA++;
                else if (sg[k2] == gB) cB++;
            }
            meta[0] = gA; meta[1] = gB; meta[2] = cA; meta[3] = cB;
        }
        __syncthreads();
        int gA = meta[0], gB = meta[1];
        int myg = valid ? sg[slot] : -2;

        bool inA = valid && (myg == gA);
        ((float4*)(lpool + slot * 32))[ln] =
            inA ? acc : make_float4(0.f, 0.f, 0.f, 0.f);
        __syncthreads();
        if (threadIdx.x < 32) {
            float ssum = 0.f;
#pragma unroll
            for (int k2 = 0; k2 < 32; k2++) ssum += lpool[k2 * 32 + threadIdx.x];
            atomicAdd(&gsum[gA * DIM + cg * 32 + threadIdx.x], ssum);
        }
        if (threadIdx.x == 0 && cg == 0) atomicAdd(&cnt[gA], (float)meta[2]);

        if (gB != gA) {
            __syncthreads();
            bool inB = valid && (myg == gB);
            ((float4*)(lpool + slot * 32))[ln] =
                inB ? acc : make_float4(0.f, 0.f, 0.f, 0.f);
            __syncthreads();
            if (threadIdx.x < 32) {
                float ssum = 0.f;
#pragma unroll
                for (int k2 = 0; k2 < 32; k2++) ssum += lpool[k2 * 32 + threadIdx.x];
                atomicAdd(&gsum[gB * DIM + cg * 32 + threadIdx.x], ssum);
            }
            if (threadIdx.x == 0 && cg == 0) atomicAdd(&cnt[gB], (float)meta[3]);
        }

        if (valid && myg != gA && myg != gB) {
            float* o = gsum + (size_t)myg * DIM + cg * 32 + ln * 4;
            atomicAdd(o + 0, acc.x);
            atomicAdd(o + 1, acc.y);
            atomicAdd(o + 2, acc.z);
            atomicAdd(o + 3, acc.w);
            if (ln == 0 && cg == 0) atomicAdd(&cnt[myg], 1.0f);
        }
    } else {
        if (valid) {
            __half2 p01 = __floats2half2_rn(acc.x, acc.y);
            __half2 p23 = __floats2half2_rn(acc.z, acc.w);
            uint2 o;
            o.x = *reinterpret_cast<unsigned int*>(&p01);
            o.y = *reinterpret_cast<unsigned int*>(&p23);
            // plane-blocked output (consumed by k_gemm_mfma<_Float16>)
            ((uint2*)OUT)[((size_t)cg * n + i) * 8 + ln] = o;
        }
    }
}

// ================= classifier =================

__global__ __launch_bounds__(128) void k_classifier(const float* __restrict__ gsum,
                                                    const float* __restrict__ cnt,
                                                    const float* __restrict__ Wc1,
                                                    const float* __restrict__ bc1,
                                                    const float* __restrict__ Wc2,
                                                    const float* __restrict__ bc2,
                                                    float* __restrict__ out) {
    int g = blockIdx.x;
    int t = threadIdx.x;  // 128
    __shared__ float gv[128];
    __shared__ float hid[128];
    float inv = 1.0f / fmaxf(cnt[g], 1.0f);
    gv[t] = gsum[(size_t)g * DIM + t] * inv;
    __syncthreads();
    float acc = bc1[t];
    for (int k = 0; k < 128; k++) acc += gv[k] * Wc1[k * 128 + t];
    hid[t] = fmaxf(acc, 0.f);
    __syncthreads();
    if (t < 4) {
        float o = bc2[t];
        for (int k = 0; k < 128; k++) o += hid[k] * Wc2[k * 4 + t];
        out[g * 4 + t] = o;
    }
}

// ================= launch =================

extern "C" void kernel_launch(void* const* d_in, const int* in_sizes, int n_in,
                              void* d_out, int out_size, void* d_ws, size_t ws_size,
                              hipStream_t stream) {
    const float* x     = (const float*)d_in[0];
    const int*   ei    = (const int*)d_in[1];  // [2, E]: src then dst
    const float* attr  = (const float*)d_in[2];
    // d_in[3] edge_weight: unused by reference
    const int*   batch = (const int*)d_in[4];
    const float* W0  = (const float*)d_in[5];
    const float* b0  = (const float*)d_in[6];
    const float* W1  = (const float*)d_in[7];
    const float* b1  = (const float*)d_in[8];
    const float* Wc1 = (const float*)d_in[9];
    const float* bc1 = (const float*)d_in[10];
    const float* Wc2 = (const float*)d_in[11];
    const float* bc2 = (const float*)d_in[12];
    float* out = (float*)d_out;

    char* ws = (char*)d_ws;
    __half*             bufH16 = (__half*)(ws + 0);                  // 12,800,000
    __half*             bufA16 = (__half*)(ws + 12800000);           // 12,800,000
    unsigned int*       epack  = (unsigned int*)(ws + 25600000);     // 12,800,000
    unsigned long long* packed = (unsigned long long*)(ws + 38400000);  // 8*6272*8 = 401,408
    float*              gsum   = (float*)(ws + 38801408);            //     65,536
    float*              cnt    = (float*)(ws + 38866944);            //        512
    _Float16*           Wt0    = (_Float16*)(ws + 38867456);         //     32,768
    _Float16*           Wt1    = (_Float16*)(ws + 38900224);         //     32,768

    const int* src = ei;
    const int* dst = ei + N_EDGES;

    const int NB_C = (N_EDGES + 255) / 256;            // 3125 chunks
    const int NB_G = ((N_NODES + 31) / 32) * 4;        // 1563 node-blocks x 4 cg
    const int NB_M = (N_NODES + 63) / 64;              // 782

    // zero packed+gsum+cnt (contiguous 467,456 B) without a kernel launch
    (void)hipMemsetAsync(ws + 38400000, 0, 467456, stream);

    // one-pass CSR build + W transpose (un-sliced, R19)
    k_build<<<NB_C + 128, 256, 0, stream>>>(src, dst, attr, W0, W1, packed,
                                            epack, Wt0, Wt1, N_EDGES, NB_C);

    // layer 1: MFMA gemm (H' = dinv*(x@W0), fp16, plane-blocked) + gather
    k_gemm_mfma<float><<<NB_M, 256, 0, stream>>>(x, Wt0, packed, bufH16, N_NODES);
    k_gather<false><<<NB_G, 256, 0, stream>>>(bufH16, packed, epack, b0,
                                              batch, bufA16, gsum, cnt, N_NODES);

    // layer 2: MFMA gemm (fp16 plane-blocked A) + gather w/ segmented pool
    k_gemm_mfma<_Float16><<<NB_M, 256, 0, stream>>>((const _Float16*)bufA16, Wt1,
                                                    packed, bufH16, N_NODES);
    k_gather<true><<<NB_G, 256, 0, stream>>>(bufH16, packed, epack, b1,
                                             batch, nullptr, gsum, cnt, N_NODES);

    // classifier
    k_classifier<<<NUM_GRAPHS, 128, 0, stream>>>(gsum, cnt, Wc1, bc1, Wc2, bc2, out);
}

// Round 6
// 257.602 us; speedup vs baseline: 1.0098x; 1.0098x over previous
//
#include <hip/hip_runtime.h>
#include <hip/hip_fp16.h>

#define N_NODES 50000
#define N_EDGES 800000
#define DIM 128
#define NUM_GRAPHS 128
#define STRIDE 64                      // CSR slot stride (>= max in-degree)
#define PSLICE 6272                    // padded nodes/slice (392 x 128 B lines)

#define ATTR_SCALE 33554432.0f         // 2^25 fixed-point for attr sums
#define ATTR_MASK  ((1ull << 40) - 1)

typedef _Float16 f16x8 __attribute__((ext_vector_type(8)));
typedef float f32x4 __attribute__((ext_vector_type(4)));

// ===========================================================================
// H / A layout (R15): COLUMN-PLANE-BLOCKED fp16 (4 planes of [n][64 B]).
// R16 (NT epack): REGRESSED — killed cross-cg L2 reuse. Plain loads.
// R17 (16-wide gather): NEUTRAL — not latency-bound (key evidence for R20).
// R18 (slice-grouped packed): NULL — atomics execute memory-side; XCD
//   affinity irrelevant. Layout kept (harmless).
// R19 (un-sliced build): NULL on dur (~50 us invariant across 2 structures
//   with 8x different wave count / fetch) -> k_build is bound by the 800K
//   atomic RMWs themselves (~16 G atomics/s ceiling). Reverted to sliced
//   form (better epack write locality: WRITE 33 vs 48 MB).
// R20: LDS-DECODED GATHER. Old gather decoded each epack word in all 8
//   lanes of the group x 4 cgs = 32 redundant lane-decodes/edge; VALU 34%
//   busy on overhead while FMA work is ~3 us. Phase 1: 256 threads decode
//   the block's edges once into LDS [k][slot] as (node*8, wt_f32). Phase 2:
//   groups stream via broadcast ds_read_b64 + plane gather + FMA.
// ===========================================================================

__device__ __forceinline__ int pidx(int d) {
    return (d & 7) * PSLICE + (d >> 3);
}

// ===== fused CSR build + W-transpose, XCD-sliced (R4/R14 state) ============

__global__ __launch_bounds__(256) void k_build(const int* __restrict__ src,
                                               const int* __restrict__ dst,
                                               const float* __restrict__ attr,
                                               const float* __restrict__ W0,
                                               const float* __restrict__ W1,
                                               unsigned long long* packed,
                                               unsigned int* __restrict__ epack,
                                               _Float16* __restrict__ Wt0,
                                               _Float16* __restrict__ Wt1,
                                               int E, int nbChunks) {
    int b = blockIdx.x;
    if (b >= nbChunks * 8) {
        int idx = (b - nbChunks * 8) * 256 + threadIdx.x;  // 32768 = 2*128*128
        int m = idx >> 14;
        int rem = idx & 16383;
        int n = rem >> 7;
        int k = rem & 127;
        const float* W = m ? W1 : W0;
        _Float16* Wt = m ? Wt1 : Wt0;
        Wt[(size_t)n * 128 + k] = (_Float16)W[(size_t)k * 128 + n];
        return;
    }
    int slice = b & 7;
    int e = (b >> 3) * 256 + threadIdx.x;
    if (e >= E) return;
    int d = dst[e];
    if ((d & 7) != slice) return;
    float a = attr[e];
    unsigned long long add =
        (1ull << 40) | (unsigned long long)(unsigned int)(a * ATTR_SCALE + 0.5f);
    unsigned long long old = atomicAdd(&packed[pidx(d)], add);
    int rank = (int)(old >> 40);
    if (rank < STRIDE) {
        __half ha = __float2half_rn(a);
        unsigned short us = *reinterpret_cast<unsigned short*>(&ha);
        epack[d * STRIDE + rank] = ((unsigned int)us << 16) | (unsigned int)src[e];
    }
}

// ===== MFMA f16 GEMM, operand-swapped ======================================
// float path (layer 1): A = x, row-major fp32 (external input).
// f16 path (layer 2):   A = bufA16, PLANE-BLOCKED (written by k_gather<false>).
// H output: PLANE-BLOCKED. colq = quad + 4t -> plane (colq>>3), offset colq&7.

template <typename AT>
__global__ __launch_bounds__(256) void k_gemm_mfma(const AT* __restrict__ A,
                                                   const _Float16* __restrict__ Wt,
                                                   const unsigned long long* __restrict__ packed,
                                                   __half* __restrict__ H, int n) {
    int tid = threadIdx.x;
    int w = tid >> 6, lane = tid & 63;
    int n15 = lane & 15, quad = lane >> 4;
    int node = blockIdx.x * 64 + w * 16 + n15;
    int nodec = node < n ? node : n - 1;
    const AT* Arow = A + (size_t)nodec * DIM;   // used by float path only

    f32x4 acc[8];
#pragma unroll
    for (int t = 0; t < 8; t++) acc[t] = (f32x4){0.f, 0.f, 0.f, 0.f};

#pragma unroll
    for (int c = 0; c < 4; c++) {
        f16x8 bf;
        if constexpr (__is_same(AT, float)) {
            float4 a0 = ((const float4*)Arow)[c * 8 + quad * 2];
            float4 a1 = ((const float4*)Arow)[c * 8 + quad * 2 + 1];
            bf[0] = (_Float16)a0.x; bf[1] = (_Float16)a0.y;
            bf[2] = (_Float16)a0.z; bf[3] = (_Float16)a0.w;
            bf[4] = (_Float16)a1.x; bf[5] = (_Float16)a1.y;
            bf[6] = (_Float16)a1.z; bf[7] = (_Float16)a1.w;
        } else {
            // plane-blocked read: f16x8 = 2 uint2 at plane c, offset quad*2.
            const uint2* Ab = reinterpret_cast<const uint2*>(A);
            bf = *(const f16x8*)&Ab[((size_t)c * n + nodec) * 8 + quad * 2];
        }
#pragma unroll
        for (int t = 0; t < 8; t++) {
            f16x8 af = *(const f16x8*)(Wt + (size_t)(t * 16 + n15) * 128 + c * 32 + quad * 8);
            acc[t] = __builtin_amdgcn_mfma_f32_16x16x32_f16(af, bf, acc[t], 0, 0, 0);
        }
    }

    if (node < n) {
        unsigned long long pk = packed[pidx(nodec)];
        float dv = rsqrtf(1.0f + (float)(pk & ATTR_MASK) * (1.0f / ATTR_SCALE));
        uint2* Hb = (uint2*)H;
#pragma unroll
        for (int t = 0; t < 8; t++) {
            __half2 h01 = __floats2half2_rn(acc[t][0] * dv, acc[t][1] * dv);
            __half2 h23 = __floats2half2_rn(acc[t][2] * dv, acc[t][3] * dv);
            uint2 pkd;
            pkd.x = *reinterpret_cast<unsigned int*>(&h01);
            pkd.y = *reinterpret_cast<unsigned int*>(&h23);
            int colq = quad + 4 * t;
            Hb[((size_t)(colq >> 3) * n + node) * 8 + (colq & 7)] = pkd;
        }
    }
}

// ===== COLUMN-SLICED gather, plane-blocked H, LDS-decoded (R20) ============

__device__ __forceinline__ float2 unpack_h2(unsigned int u) {
    __half2 h = *reinterpret_cast<__half2*>(&u);
    return __half22float2(h);
}

template <bool POOL>
__global__ __launch_bounds__(256) void k_gather(const __half* __restrict__ H,
                                                const unsigned long long* __restrict__ packed,
                                                const unsigned int* __restrict__ epack,
                                                const float* __restrict__ bias,
                                                const int* __restrict__ batch,
                                                __half* __restrict__ OUT,
                                                float* gsum, float* cnt, int n) {
    int cg = blockIdx.x & 3;           // column group == plane (XCD-affine)
    int nb = blockIdx.x >> 2;          // node-block (32 nodes)
    int tid = threadIdx.x;

    // [k][slot] pre-decoded edges: .x = src_node*8 (uint2 idx), .y = wt bits
    __shared__ uint2 elds[STRIDE * 32];     // 16 KB
    __shared__ float dv_lds[32];
    __shared__ int   cr_lds[32];

    // ---- phase 1: cooperative decode, one thread per (slot, k-lane) ----
    {
        int slot = tid & 31;
        int kb = tid >> 5;                 // 0..7
        int i1 = nb * 32 + slot;
        int ic1 = (i1 < n) ? i1 : n - 1;
        unsigned long long pk = packed[pidx(ic1)];
        int ce = (i1 < n) ? (int)(pk >> 40) : 0;
        if (ce > STRIDE) ce = STRIDE;
        int cr = (ce + 7) & ~7;            // rounded up to 8
        if (kb == 0) {
            cr_lds[slot] = cr;
            dv_lds[slot] = rsqrtf(1.0f + (float)(pk & ATTR_MASK) * (1.0f / ATTR_SCALE));
        }
        const unsigned int* ep = epack + ic1 * STRIDE;
        for (int k = kb; k < cr; k += 8) {
            // padding slots decode pe=0 -> s=0 (valid row), wt=+0.0 (exact 0)
            unsigned int pe = (k < ce) ? ep[k] : 0u;
            __half_raw hr;
            hr.x = (unsigned short)(pe >> 16);
            float wv = __half2float(__half(hr));
            elds[k * 32 + slot] = make_uint2((pe & 0xffffu) * 8u, __float_as_uint(wv));
        }
    }
    __syncthreads();

    // ---- phase 2: 8 lanes/node stream pre-decoded edges ----
    int slot = tid >> 3;               // node slot [0,32)
    int ln = tid & 7;                  // lane in group [0,8)
    int i = nb * 32 + slot;
    bool valid = i < n;
    int ic = valid ? i : n - 1;
    int colq = cg * 8 + ln;            // logical uint2 column [0,32) (bias/pool)
    const uint2* Hp = (const uint2*)H + (size_t)cg * n * 8;   // this cg's plane

    float dv = dv_lds[slot];
    int cr = cr_lds[slot];

    uint2 selfraw = Hp[(size_t)ic * 8 + ln];
    float2 s01 = unpack_h2(selfraw.x);
    float2 s23 = unpack_h2(selfraw.y);
    float4 acc = make_float4(s01.x, s01.y, s23.x, s23.y);

    for (int j = 0; j < cr; j += 8) {
        uint2 e[8];
#pragma unroll
        for (int k = 0; k < 8; k++) e[k] = elds[(j + k) * 32 + slot];  // broadcast
        uint2 v[8];
#pragma unroll
        for (int k = 0; k < 8; k++) v[k] = Hp[e[k].x + ln];
#pragma unroll
        for (int k = 0; k < 8; k++) {
            float wt = __uint_as_float(e[k].y);
            float2 f01 = unpack_h2(v[k].x);
            float2 f23 = unpack_h2(v[k].y);
            acc.x += wt * f01.x;
            acc.y += wt * f01.y;
            acc.z += wt * f23.x;
            acc.w += wt * f23.y;
        }
    }

    float4 bb = ((const float4*)bias)[colq];
    acc.x = fmaxf(acc.x * dv + bb.x, 0.f);
    acc.y = fmaxf(acc.y * dv + bb.y, 0.f);
    acc.z = fmaxf(acc.z * dv + bb.z, 0.f);
    acc.w = fmaxf(acc.w * dv + bb.w, 0.f);

    if constexpr (POOL) {
        __shared__ float lpool[32 * 32];  // 32 nodes x 32 feats (this cg)
        __shared__ int sg[32];
        __shared__ int meta[4];           // gA, gB, cntA, cntB
        if (ln == 0) sg[slot] = valid ? batch[ic] : -1;
        __syncthreads();
        if (tid == 0) {
            int nv = n - nb * 32; if (nv > 32) nv = 32;
            int gA = sg[0];
            int gB = sg[nv - 1];
            int cA = 0, cB = 0;
            for (int k2 = 0; k2 < nv; k2++) {
                if (sg[k2] == gA) cA++;
                else if (sg[k2] == gB) cB++;
            }
            meta[0] = gA; meta[1] = gB; meta[2] = cA; meta[3] = cB;
        }
        __syncthreads();
        int gA = meta[0], gB = meta[1];
        int myg = valid ? sg[slot] : -2;

        bool inA = valid && (myg == gA);
        ((float4*)(lpool + slot * 32))[ln] =
            inA ? acc : make_float4(0.f, 0.f, 0.f, 0.f);
        __syncthreads();
        if (tid < 32) {
            float ssum = 0.f;
#pragma unroll
            for (int k2 = 0; k2 < 32; k2++) ssum += lpool[k2 * 32 + tid];
            atomicAdd(&gsum[gA * DIM + cg * 32 + tid], ssum);
        }
        if (tid == 0 && cg == 0) atomicAdd(&cnt[gA], (float)meta[2]);

        if (gB != gA) {
            __syncthreads();
            bool inB = valid && (myg == gB);
            ((float4*)(lpool + slot * 32))[ln] =
                inB ? acc : make_float4(0.f, 0.f, 0.f, 0.f);
            __syncthreads();
            if (tid < 32) {
                float ssum = 0.f;
#pragma unroll
                for (int k2 = 0; k2 < 32; k2++) ssum += lpool[k2 * 32 + tid];
                atomicAdd(&gsum[gB * DIM + cg * 32 + tid], ssum);
            }
            if (tid == 0 && cg == 0) atomicAdd(&cnt[gB], (float)meta[3]);
        }

        if (valid && myg != gA && myg != gB) {
            float* o = gsum + (size_t)myg * DIM + cg * 32 + ln * 4;
            atomicAdd(o + 0, acc.x);
            atomicAdd(o + 1, acc.y);
            atomicAdd(o + 2, acc.z);
            atomicAdd(o + 3, acc.w);
            if (ln == 0 && cg == 0) atomicAdd(&cnt[myg], 1.0f);
        }
    } else {
        if (valid) {
            __half2 p01 = __floats2half2_rn(acc.x, acc.y);
            __half2 p23 = __floats2half2_rn(acc.z, acc.w);
            uint2 o;
            o.x = *reinterpret_cast<unsigned int*>(&p01);
            o.y = *reinterpret_cast<unsigned int*>(&p23);
            // plane-blocked output (consumed by k_gemm_mfma<_Float16>)
            ((uint2*)OUT)[((size_t)cg * n + i) * 8 + ln] = o;
        }
    }
}

// ================= classifier =================

__global__ __launch_bounds__(128) void k_classifier(const float* __restrict__ gsum,
                                                    const float* __restrict__ cnt,
                                                    const float* __restrict__ Wc1,
                                                    const float* __restrict__ bc1,
                                                    const float* __restrict__ Wc2,
                                                    const float* __restrict__ bc2,
                                                    float* __restrict__ out) {
    int g = blockIdx.x;
    int t = threadIdx.x;  // 128
    __shared__ float gv[128];
    __shared__ float hid[128];
    float inv = 1.0f / fmaxf(cnt[g], 1.0f);
    gv[t] = gsum[(size_t)g * DIM + t] * inv;
    __syncthreads();
    float acc = bc1[t];
    for (int k = 0; k < 128; k++) acc += gv[k] * Wc1[k * 128 + t];
    hid[t] = fmaxf(acc, 0.f);
    __syncthreads();
    if (t < 4) {
        float o = bc2[t];
        for (int k = 0; k < 128; k++) o += hid[k] * Wc2[k * 4 + t];
        out[g * 4 + t] = o;
    }
}

// ================= launch =================

extern "C" void kernel_launch(void* const* d_in, const int* in_sizes, int n_in,
                              void* d_out, int out_size, void* d_ws, size_t ws_size,
                              hipStream_t stream) {
    const float* x     = (const float*)d_in[0];
    const int*   ei    = (const int*)d_in[1];  // [2, E]: src then dst
    const float* attr  = (const float*)d_in[2];
    // d_in[3] edge_weight: unused by reference
    const int*   batch = (const int*)d_in[4];
    const float* W0  = (const float*)d_in[5];
    const float* b0  = (const float*)d_in[6];
    const float* W1  = (const float*)d_in[7];
    const float* b1  = (const float*)d_in[8];
    const float* Wc1 = (const float*)d_in[9];
    const float* bc1 = (const float*)d_in[10];
    const float* Wc2 = (const float*)d_in[11];
    const float* bc2 = (const float*)d_in[12];
    float* out = (float*)d_out;

    char* ws = (char*)d_ws;
    __half*             bufH16 = (__half*)(ws + 0);                  // 12,800,000
    __half*             bufA16 = (__half*)(ws + 12800000);           // 12,800,000
    unsigned int*       epack  = (unsigned int*)(ws + 25600000);     // 12,800,000
    unsigned long long* packed = (unsigned long long*)(ws + 38400000);  // 8*6272*8 = 401,408
    float*              gsum   = (float*)(ws + 38801408);            //     65,536
    float*              cnt    = (float*)(ws + 38866944);            //        512
    _Float16*           Wt0    = (_Float16*)(ws + 38867456);         //     32,768
    _Float16*           Wt1    = (_Float16*)(ws + 38900224);         //     32,768

    const int* src = ei;
    const int* dst = ei + N_EDGES;

    const int NB_C = (N_EDGES + 255) / 256;            // 3125 chunks
    const int NB_G = ((N_NODES + 31) / 32) * 4;        // 1563 node-blocks x 4 cg
    const int NB_M = (N_NODES + 63) / 64;              // 782

    // zero packed+gsum+cnt (contiguous 467,456 B) without a kernel launch
    (void)hipMemsetAsync(ws + 38400000, 0, 467456, stream);

    // XCD-sliced one-pass CSR build + W transpose (reverted to R4 state)
    k_build<<<NB_C * 8 + 128, 256, 0, stream>>>(src, dst, attr, W0, W1, packed,
                                                epack, Wt0, Wt1, N_EDGES, NB_C);

    // layer 1: MFMA gemm (H' = dinv*(x@W0), fp16, plane-blocked) + gather
    k_gemm_mfma<float><<<NB_M, 256, 0, stream>>>(x, Wt0, packed, bufH16, N_NODES);
    k_gather<false><<<NB_G, 256, 0, stream>>>(bufH16, packed, epack, b0,
                                              batch, bufA16, gsum, cnt, N_NODES);

    // layer 2: MFMA gemm (fp16 plane-blocked A) + gather w/ segmented pool
    k_gemm_mfma<_Float16><<<NB_M, 256, 0, stream>>>((const _Float16*)bufA16, Wt1,
                                                    packed, bufH16, N_NODES);
    k_gather<true><<<NB_G, 256, 0, stream>>>(bufH16, packed, epack, b1,
                                             batch, nullptr, gsum, cnt, N_NODES);

    // classifier
    k_classifier<<<NUM_GRAPHS, 128, 0, stream>>>(gsum, cnt, Wc1, bc1, Wc2, bc2, out);
}

// Round 7
// 254.895 us; speedup vs baseline: 1.0205x; 1.0106x over previous
//
#include <hip/hip_runtime.h>
#include <hip/hip_fp16.h>

#define N_NODES 50000
#define N_EDGES 800000
#define DIM 128
#define NUM_GRAPHS 128
#define STRIDE 64                      // CSR slot stride (>= max in-degree)
#define PSLICE 6272                    // padded nodes/slice (392 x 128 B lines)

#define ATTR_SCALE 33554432.0f         // 2^25 fixed-point for attr sums
#define ATTR_MASK  ((1ull << 40) - 1)

typedef _Float16 f16x8 __attribute__((ext_vector_type(8)));
typedef float f32x4 __attribute__((ext_vector_type(4)));

// ===========================================================================
// H / A layout (R15): COLUMN-PLANE-BLOCKED fp16 (4 planes of [n][64 B]).
// R16 (NT epack): REGRESSED — killed cross-cg L2 reuse. Plain loads.
// R17 (16-wide gather): NEUTRAL — not latency-bound.
// R18 (slice-grouped packed): NULL — atomics execute memory-side. Kept.
// R19 (un-sliced build): NULL — build bound by the 800K atomic RMWs
//   (~17 G atomics/s), invariant across structures. Sliced form kept.
// R20 (LDS-decoded gather): NEUTRAL — kept (decode-once enables R21).
// R21: GEMM1 FUSED INTO BUILD LAUNCH. Build is atomic-bound with VALU 7%/
//   MFMA 0% — co-schedule gemm1 (different pipes) under the atomic drain.
//   gemm1 writes UNSCALED H'' (no packed dep; W0^T self-staged via LDS
//   quarter-tiles); dinv_s moves to gather1 phase-1 (wt' = wt*dinv[s],
//   self term scaled by dv at init) via tiny k_dinv kernel after build.
//   gemm2/gather2 unchanged (dv pre-applied in gemm2 epilogue as before).
// ===========================================================================

__device__ __forceinline__ int pidx(int d) {
    return (d & 7) * PSLICE + (d >> 3);
}

// ===== fused: gemm1 (unscaled) + CSR build + Wt1 transpose =================
// Grid = [NB_M gemm blocks] [NB_C*8 CSR blocks] [64 Wt1-transpose blocks].
// Gemm blocks first -> resident early, overlap the atomic-bound CSR drain.

__global__ __launch_bounds__(256) void k_build(const float* __restrict__ x,
                                               const int* __restrict__ src,
                                               const int* __restrict__ dst,
                                               const float* __restrict__ attr,
                                               const float* __restrict__ W0,
                                               const float* __restrict__ W1,
                                               unsigned long long* packed,
                                               unsigned int* __restrict__ epack,
                                               _Float16* __restrict__ Wt1,
                                               __half* __restrict__ H,
                                               int E, int nbChunks, int nbGemm, int n) {
    // quarter-tile of W0^T: WtL[col n][kk] = W0[c*32+kk][n], kk<32, pad to 40
    __shared__ _Float16 WtL[128 * 40];   // 10,240 B
    int b = blockIdx.x;
    int tid = threadIdx.x;

    if (b < nbGemm) {
        // ---------- gemm1 path: H'' = x @ W0 (fp16, plane-blocked, NO dv) --
        int w = tid >> 6, lane = tid & 63;
        int n15 = lane & 15, quad = lane >> 4;
        int node = b * 64 + w * 16 + n15;
        int nodec = node < n ? node : n - 1;
        const float* Arow = x + (size_t)nodec * DIM;

        f32x4 acc[8];
#pragma unroll
        for (int t = 0; t < 8; t++) acc[t] = (f32x4){0.f, 0.f, 0.f, 0.f};

        for (int c = 0; c < 4; c++) {
            __syncthreads();   // protect previous quarter's readers
            {
                int sn = tid & 127, kh = tid >> 7;   // 2 k-rows per pass
#pragma unroll
                for (int it = 0; it < 16; it++) {
                    int kk = kh + it * 2;
                    WtL[sn * 40 + kk] = (_Float16)W0[(size_t)(c * 32 + kk) * 128 + sn];
                }
            }
            __syncthreads();
            f16x8 bf;
            float4 a0 = ((const float4*)Arow)[c * 8 + quad * 2];
            float4 a1 = ((const float4*)Arow)[c * 8 + quad * 2 + 1];
            bf[0] = (_Float16)a0.x; bf[1] = (_Float16)a0.y;
            bf[2] = (_Float16)a0.z; bf[3] = (_Float16)a0.w;
            bf[4] = (_Float16)a1.x; bf[5] = (_Float16)a1.y;
            bf[6] = (_Float16)a1.z; bf[7] = (_Float16)a1.w;
#pragma unroll
            for (int t = 0; t < 8; t++) {
                f16x8 af = *(const f16x8*)(WtL + (t * 16 + n15) * 40 + quad * 8);
                acc[t] = __builtin_amdgcn_mfma_f32_16x16x32_f16(af, bf, acc[t], 0, 0, 0);
            }
        }

        if (node < n) {
            uint2* Hb = (uint2*)H;
#pragma unroll
            for (int t = 0; t < 8; t++) {
                __half2 h01 = __floats2half2_rn(acc[t][0], acc[t][1]);
                __half2 h23 = __floats2half2_rn(acc[t][2], acc[t][3]);
                uint2 pkd;
                pkd.x = *reinterpret_cast<unsigned int*>(&h01);
                pkd.y = *reinterpret_cast<unsigned int*>(&h23);
                int colq = quad + 4 * t;
                Hb[((size_t)(colq >> 3) * n + node) * 8 + (colq & 7)] = pkd;
            }
        }
        return;
    }

    if (b >= nbGemm + nbChunks * 8) {
        // ---------- Wt1 transpose (16384 elements over 64 blocks) ----------
        int idx = (b - nbGemm - nbChunks * 8) * 256 + tid;
        int nn = idx >> 7;
        int kk = idx & 127;
        Wt1[(size_t)nn * 128 + kk] = (_Float16)W1[(size_t)kk * 128 + nn];
        return;
    }

    // ---------- CSR path (XCD-sliced, R4 state) ----------------------------
    int b2 = b - nbGemm;
    int slice = b2 & 7;
    int e = (b2 >> 3) * 256 + tid;
    if (e >= E) return;
    int d = dst[e];
    if ((d & 7) != slice) return;
    float a = attr[e];
    unsigned long long add =
        (1ull << 40) | (unsigned long long)(unsigned int)(a * ATTR_SCALE + 0.5f);
    unsigned long long old = atomicAdd(&packed[pidx(d)], add);
    int rank = (int)(old >> 40);
    if (rank < STRIDE) {
        __half ha = __float2half_rn(a);
        unsigned short us = *reinterpret_cast<unsigned short*>(&ha);
        epack[d * STRIDE + rank] = ((unsigned int)us << 16) | (unsigned int)src[e];
    }
}

// ===== dinv materialization (after build, before gather1) ==================

__global__ __launch_bounds__(256) void k_dinv(const unsigned long long* __restrict__ packed,
                                              float* __restrict__ dinv, int n) {
    int i = blockIdx.x * 256 + threadIdx.x;
    if (i < n) {
        unsigned long long pk = packed[pidx(i)];
        dinv[i] = rsqrtf(1.0f + (float)(pk & ATTR_MASK) * (1.0f / ATTR_SCALE));
    }
}

// ===== MFMA f16 GEMM, operand-swapped (layer 2 only now) ===================
// A = bufA16, PLANE-BLOCKED; dv applied in epilogue (packed available).

template <typename AT>
__global__ __launch_bounds__(256) void k_gemm_mfma(const AT* __restrict__ A,
                                                   const _Float16* __restrict__ Wt,
                                                   const unsigned long long* __restrict__ packed,
                                                   __half* __restrict__ H, int n) {
    int tid = threadIdx.x;
    int w = tid >> 6, lane = tid & 63;
    int n15 = lane & 15, quad = lane >> 4;
    int node = blockIdx.x * 64 + w * 16 + n15;
    int nodec = node < n ? node : n - 1;
    const AT* Arow = A + (size_t)nodec * DIM;   // used by float path only

    f32x4 acc[8];
#pragma unroll
    for (int t = 0; t < 8; t++) acc[t] = (f32x4){0.f, 0.f, 0.f, 0.f};

#pragma unroll
    for (int c = 0; c < 4; c++) {
        f16x8 bf;
        if constexpr (__is_same(AT, float)) {
            float4 a0 = ((const float4*)Arow)[c * 8 + quad * 2];
            float4 a1 = ((const float4*)Arow)[c * 8 + quad * 2 + 1];
            bf[0] = (_Float16)a0.x; bf[1] = (_Float16)a0.y;
            bf[2] = (_Float16)a0.z; bf[3] = (_Float16)a0.w;
            bf[4] = (_Float16)a1.x; bf[5] = (_Float16)a1.y;
            bf[6] = (_Float16)a1.z; bf[7] = (_Float16)a1.w;
        } else {
            const uint2* Ab = reinterpret_cast<const uint2*>(A);
            bf = *(const f16x8*)&Ab[((size_t)c * n + nodec) * 8 + quad * 2];
        }
#pragma unroll
        for (int t = 0; t < 8; t++) {
            f16x8 af = *(const f16x8*)(Wt + (size_t)(t * 16 + n15) * 128 + c * 32 + quad * 8);
            acc[t] = __builtin_amdgcn_mfma_f32_16x16x32_f16(af, bf, acc[t], 0, 0, 0);
        }
    }

    if (node < n) {
        unsigned long long pk = packed[pidx(nodec)];
        float dv = rsqrtf(1.0f + (float)(pk & ATTR_MASK) * (1.0f / ATTR_SCALE));
        uint2* Hb = (uint2*)H;
#pragma unroll
        for (int t = 0; t < 8; t++) {
            __half2 h01 = __floats2half2_rn(acc[t][0] * dv, acc[t][1] * dv);
            __half2 h23 = __floats2half2_rn(acc[t][2] * dv, acc[t][3] * dv);
            uint2 pkd;
            pkd.x = *reinterpret_cast<unsigned int*>(&h01);
            pkd.y = *reinterpret_cast<unsigned int*>(&h23);
            int colq = quad + 4 * t;
            Hb[((size_t)(colq >> 3) * n + node) * 8 + (colq & 7)] = pkd;
        }
    }
}

// ===== COLUMN-SLICED gather, plane-blocked H, LDS-decoded ==================
// SRCS=true (layer 1): H is unscaled; fold dinv[s] into wt in phase 1 and
// scale the self term by dv at init. SRCS=false (layer 2): dv pre-applied.

__device__ __forceinline__ float2 unpack_h2(unsigned int u) {
    __half2 h = *reinterpret_cast<__half2*>(&u);
    return __half22float2(h);
}

template <bool POOL, bool SRCS>
__global__ __launch_bounds__(256) void k_gather(const __half* __restrict__ H,
                                                const unsigned long long* __restrict__ packed,
                                                const unsigned int* __restrict__ epack,
                                                const float* __restrict__ dinv_arr,
                                                const float* __restrict__ bias,
                                                const int* __restrict__ batch,
                                                __half* __restrict__ OUT,
                                                float* gsum, float* cnt, int n) {
    int cg = blockIdx.x & 3;           // column group == plane (XCD-affine)
    int nb = blockIdx.x >> 2;          // node-block (32 nodes)
    int tid = threadIdx.x;

    // [k][slot] pre-decoded edges: .x = src_node*8 (uint2 idx), .y = wt bits
    __shared__ uint2 elds[STRIDE * 32];     // 16 KB
    __shared__ float dv_lds[32];
    __shared__ int   cr_lds[32];

    // ---- phase 1: cooperative decode, one thread per (slot, k-lane) ----
    {
        int slot = tid & 31;
        int kb = tid >> 5;                 // 0..7
        int i1 = nb * 32 + slot;
        int ic1 = (i1 < n) ? i1 : n - 1;
        unsigned long long pk = packed[pidx(ic1)];
        int ce = (i1 < n) ? (int)(pk >> 40) : 0;
        if (ce > STRIDE) ce = STRIDE;
        int cr = (ce + 7) & ~7;            // rounded up to 8
        if (kb == 0) {
            cr_lds[slot] = cr;
            dv_lds[slot] = rsqrtf(1.0f + (float)(pk & ATTR_MASK) * (1.0f / ATTR_SCALE));
        }
        const unsigned int* ep = epack + ic1 * STRIDE;
        for (int k = kb; k < cr; k += 8) {
            // padding slots decode pe=0 -> s=0 (valid row), wt=+0.0 (exact 0)
            unsigned int pe = (k < ce) ? ep[k] : 0u;
            __half_raw hr;
            hr.x = (unsigned short)(pe >> 16);
            float wv = __half2float(__half(hr));
            if (SRCS) wv *= dinv_arr[pe & 0xffffu];   // fold dinv_s (0*d=0 ok)
            elds[k * 32 + slot] = make_uint2((pe & 0xffffu) * 8u, __float_as_uint(wv));
        }
    }
    __syncthreads();

    // ---- phase 2: 8 lanes/node stream pre-decoded edges ----
    int slot = tid >> 3;               // node slot [0,32)
    int ln = tid & 7;                  // lane in group [0,8)
    int i = nb * 32 + slot;
    bool valid = i < n;
    int ic = valid ? i : n - 1;
    int colq = cg * 8 + ln;            // logical uint2 column [0,32) (bias/pool)
    const uint2* Hp = (const uint2*)H + (size_t)cg * n * 8;   // this cg's plane

    float dv = dv_lds[slot];
    int cr = cr_lds[slot];

    uint2 selfraw = Hp[(size_t)ic * 8 + ln];
    float2 s01 = unpack_h2(selfraw.x);
    float2 s23 = unpack_h2(selfraw.y);
    float4 acc = make_float4(s01.x, s01.y, s23.x, s23.y);
    if (SRCS) {                        // self term: dv * h''_i (then *dv at end)
        acc.x *= dv; acc.y *= dv; acc.z *= dv; acc.w *= dv;
    }

    for (int j = 0; j < cr; j += 8) {
        uint2 e[8];
#pragma unroll
        for (int k = 0; k < 8; k++) e[k] = elds[(j + k) * 32 + slot];  // broadcast
        uint2 v[8];
#pragma unroll
        for (int k = 0; k < 8; k++) v[k] = Hp[e[k].x + ln];
#pragma unroll
        for (int k = 0; k < 8; k++) {
            float wt = __uint_as_float(e[k].y);
            float2 f01 = unpack_h2(v[k].x);
            float2 f23 = unpack_h2(v[k].y);
            acc.x += wt * f01.x;
            acc.y += wt * f01.y;
            acc.z += wt * f23.x;
            acc.w += wt * f23.y;
        }
    }

    float4 bb = ((const float4*)bias)[colq];
    acc.x = fmaxf(acc.x * dv + bb.x, 0.f);
    acc.y = fmaxf(acc.y * dv + bb.y, 0.f);
    acc.z = fmaxf(acc.z * dv + bb.z, 0.f);
    acc.w = fmaxf(acc.w * dv + bb.w, 0.f);

    if constexpr (POOL) {
        __shared__ float lpool[32 * 32];  // 32 nodes x 32 feats (this cg)
        __shared__ int sg[32];
        __shared__ int meta[4];           // gA, gB, cntA, cntB
        if (ln == 0) sg[slot] = valid ? batch[ic] : -1;
        __syncthreads();
        if (tid == 0) {
            int nv = n - nb * 32; if (nv > 32) nv = 32;
            int gA = sg[0];
            int gB = sg[nv - 1];
            int cA = 0, cB = 0;
            for (int k2 = 0; k2 < nv; k2++) {
                if (sg[k2] == gA) cA++;
                else if (sg[k2] == gB) cB++;
            }
            meta[0] = gA; meta[1] = gB; meta[2] = cA; meta[3] = cB;
        }
        __syncthreads();
        int gA = meta[0], gB = meta[1];
        int myg = valid ? sg[slot] : -2;

        bool inA = valid && (myg == gA);
        ((float4*)(lpool + slot * 32))[ln] =
            inA ? acc : make_float4(0.f, 0.f, 0.f, 0.f);
        __syncthreads();
        if (tid < 32) {
            float ssum = 0.f;
#pragma unroll
            for (int k2 = 0; k2 < 32; k2++) ssum += lpool[k2 * 32 + tid];
            atomicAdd(&gsum[gA * DIM + cg * 32 + tid], ssum);
        }
        if (tid == 0 && cg == 0) atomicAdd(&cnt[gA], (float)meta[2]);

        if (gB != gA) {
            __syncthreads();
            bool inB = valid && (myg == gB);
            ((float4*)(lpool + slot * 32))[ln] =
                inB ? acc : make_float4(0.f, 0.f, 0.f, 0.f);
            __syncthreads();
            if (tid < 32) {
                float ssum = 0.f;
#pragma unroll
                for (int k2 = 0; k2 < 32; k2++) ssum += lpool[k2 * 32 + tid];
                atomicAdd(&gsum[gB * DIM + cg * 32 + tid], ssum);
            }
            if (tid == 0 && cg == 0) atomicAdd(&cnt[gB], (float)meta[3]);
        }

        if (valid && myg != gA && myg != gB) {
            float* o = gsum + (size_t)myg * DIM + cg * 32 + ln * 4;
            atomicAdd(o + 0, acc.x);
            atomicAdd(o + 1, acc.y);
            atomicAdd(o + 2, acc.z);
            atomicAdd(o + 3, acc.w);
            if (ln == 0 && cg == 0) atomicAdd(&cnt[myg], 1.0f);
        }
    } else {
        if (valid) {
            __half2 p01 = __floats2half2_rn(acc.x, acc.y);
            __half2 p23 = __floats2half2_rn(acc.z, acc.w);
            uint2 o;
            o.x = *reinterpret_cast<unsigned int*>(&p01);
            o.y = *reinterpret_cast<unsigned int*>(&p23);
            // plane-blocked output (consumed by k_gemm_mfma<_Float16>)
            ((uint2*)OUT)[((size_t)cg * n + i) * 8 + ln] = o;
        }
    }
}

// ================= classifier =================

__global__ __launch_bounds__(128) void k_classifier(const float* __restrict__ gsum,
                                                    const float* __restrict__ cnt,
                                                    const float* __restrict__ Wc1,
                                                    const float* __restrict__ bc1,
                                                    const float* __restrict__ Wc2,
                                                    const float* __restrict__ bc2,
                                                    float* __restrict__ out) {
    int g = blockIdx.x;
    int t = threadIdx.x;  // 128
    __shared__ float gv[128];
    __shared__ float hid[128];
    float inv = 1.0f / fmaxf(cnt[g], 1.0f);
    gv[t] = gsum[(size_t)g * DIM + t] * inv;
    __syncthreads();
    float acc = bc1[t];
    for (int k = 0; k < 128; k++) acc += gv[k] * Wc1[k * 128 + t];
    hid[t] = fmaxf(acc, 0.f);
    __syncthreads();
    if (t < 4) {
        float o = bc2[t];
        for (int k = 0; k < 128; k++) o += hid[k] * Wc2[k * 4 + t];
        out[g * 4 + t] = o;
    }
}

// ================= launch =================

extern "C" void kernel_launch(void* const* d_in, const int* in_sizes, int n_in,
                              void* d_out, int out_size, void* d_ws, size_t ws_size,
                              hipStream_t stream) {
    const float* x     = (const float*)d_in[0];
    const int*   ei    = (const int*)d_in[1];  // [2, E]: src then dst
    const float* attr  = (const float*)d_in[2];
    // d_in[3] edge_weight: unused by reference
    const int*   batch = (const int*)d_in[4];
    const float* W0  = (const float*)d_in[5];
    const float* b0  = (const float*)d_in[6];
    const float* W1  = (const float*)d_in[7];
    const float* b1  = (const float*)d_in[8];
    const float* Wc1 = (const float*)d_in[9];
    const float* bc1 = (const float*)d_in[10];
    const float* Wc2 = (const float*)d_in[11];
    const float* bc2 = (const float*)d_in[12];
    float* out = (float*)d_out;

    char* ws = (char*)d_ws;
    __half*             bufH16 = (__half*)(ws + 0);                  // 12,800,000
    __half*             bufA16 = (__half*)(ws + 12800000);           // 12,800,000
    unsigned int*       epack  = (unsigned int*)(ws + 25600000);     // 12,800,000
    unsigned long long* packed = (unsigned long long*)(ws + 38400000);  // 8*6272*8 = 401,408
    float*              gsum   = (float*)(ws + 38801408);            //     65,536
    float*              cnt    = (float*)(ws + 38866944);            //        512
    _Float16*           Wt1    = (_Float16*)(ws + 38867456);         //     32,768
    float*              dinv   = (float*)(ws + 38900224);            //    200,000

    const int* src = ei;
    const int* dst = ei + N_EDGES;

    const int NB_C = (N_EDGES + 255) / 256;            // 3125 chunks
    const int NB_G = ((N_NODES + 31) / 32) * 4;        // 1563 node-blocks x 4 cg
    const int NB_M = (N_NODES + 63) / 64;              // 782
    const int NB_D = (N_NODES + 255) / 256;            // 196

    // zero packed+gsum+cnt (contiguous 467,456 B) without a kernel launch
    (void)hipMemsetAsync(ws + 38400000, 0, 467456, stream);

    // fused: gemm1 (unscaled H'') + XCD-sliced CSR build + Wt1 transpose
    k_build<<<NB_M + NB_C * 8 + 64, 256, 0, stream>>>(x, src, dst, attr, W0, W1,
                                                      packed, epack, Wt1, bufH16,
                                                      N_EDGES, NB_C, NB_M, N_NODES);

    // dinv materialization (tiny)
    k_dinv<<<NB_D, 256, 0, stream>>>(packed, dinv, N_NODES);

    // layer 1 gather: folds dinv_s into wt, dv on self + epilogue
    k_gather<false, true><<<NB_G, 256, 0, stream>>>(bufH16, packed, epack, dinv,
                                                    b0, batch, bufA16, gsum, cnt,
                                                    N_NODES);

    // layer 2: MFMA gemm (fp16 plane-blocked A, dv in epilogue) + gather/pool
    k_gemm_mfma<_Float16><<<NB_M, 256, 0, stream>>>((const _Float16*)bufA16, Wt1,
                                                    packed, bufH16, N_NODES);
    k_gather<true, false><<<NB_G, 256, 0, stream>>>(bufH16, packed, epack, dinv,
                                                    b1, batch, nullptr, gsum, cnt,
                                                    N_NODES);

    // classifier
    k_classifier<<<NUM_GRAPHS, 128, 0, stream>>>(gsum, cnt, Wc1, bc1, Wc2, bc2, out);
}